// Round 4
// baseline (174.524 us; speedup 1.0000x reference)
//
#include <hip/hip_runtime.h>

typedef unsigned short u16;
typedef __bf16 bf16x8 __attribute__((ext_vector_type(8)));
typedef unsigned short u16x8 __attribute__((ext_vector_type(8)));
typedef float f32x4 __attribute__((ext_vector_type(4)));

#define MFMA16(a, b, c) __builtin_amdgcn_mfma_f32_16x16x32_bf16((a), (b), (c), 0, 0, 0)

// same-wave LDS write->read fence: drain DS queue + block compiler reordering
#define WAVE_LDS_FENCE() do { \
  asm volatile("s_waitcnt lgkmcnt(0)" ::: "memory"); \
  __builtin_amdgcn_sched_barrier(0); \
} while (0)

// async global->LDS DMA, 16B per lane; LDS dest must be uniform base + lane*16
#define GLDS(gp, lp) __builtin_amdgcn_global_load_lds( \
    (const __attribute__((address_space(1))) unsigned int*)(gp), \
    (__attribute__((address_space(3))) unsigned int*)(lp), 16, 0, 0)

__device__ __forceinline__ u16 f2b(float f) {
  unsigned u = __float_as_uint(f);
  u += 0x7fffu + ((u >> 16) & 1u);   // RNE; inputs finite
  return (u16)(u >> 16);
}
__device__ __forceinline__ float b2f(u16 h) {
  return __uint_as_float(((unsigned)h) << 16);
}

// ---------------- converts ----------------
__global__ void cvt_bf16(const float* __restrict__ src, u16* __restrict__ dst, int n4) {
  int i = blockIdx.x * blockDim.x + threadIdx.x;
  if (i >= n4) return;
  float4 v = *(const float4*)(src + (size_t)i * 4);
  *(ushort4*)(dst + (size_t)i * 4) = make_ushort4(f2b(v.x), f2b(v.y), f2b(v.z), f2b(v.w));
}

// F[n][m][d] = Er[n][(2048 - m) % 2048][d]
__global__ void build_F(const float* __restrict__ Er, u16* __restrict__ Fb) {
  int i = blockIdx.x * blockDim.x + threadIdx.x;
  int base = i * 4;
  int d = base & 63;
  int m = (base >> 6) & 1023;
  int n = base >> 16;
  int sm = (2048 - m) & 2047;
  float4 v = *(const float4*)(Er + ((size_t)(n * 2048 + sm) * 64 + d));
  *(ushort4*)(Fb + (size_t)base) = make_ushort4(f2b(v.x), f2b(v.y), f2b(v.z), f2b(v.w));
}

// ---------------- V transpose: V[bn][i][d] -> Vt[bn][d][i] ----------------
__global__ __launch_bounds__(256) void transpose_v(const u16* __restrict__ V, u16* __restrict__ Vt) {
  __shared__ u16 T[4096];
  const int bn = blockIdx.x, i0 = blockIdx.y * 64;
  const int t = threadIdx.x;
#pragma unroll
  for (int s = 0; s < 2; ++s) {
    int ch = t + 256 * s;
    int i = ch >> 3, c = ch & 7;
    u16x8 v = *(const u16x8*)&V[(size_t)((bn << 10) + i0 + i) * 64 + c * 8];
#pragma unroll
    for (int e = 0; e < 8; ++e) {
      int d = c * 8 + e;
      T[d * 64 + ((((i >> 3) ^ (d & 7) ^ ((d >> 3) & 7)) & 7) << 3) + (i & 7)] = v[e];
    }
  }
  __syncthreads();
#pragma unroll
  for (int s = 0; s < 2; ++s) {
    int ch = t + 256 * s;
    int d = ch >> 3, cc = ch & 7;
    u16x8 o = *(const u16x8*)&T[d * 64 + (((cc ^ (d & 7) ^ ((d >> 3) & 7)) & 7) << 3)];
    *(u16x8*)&Vt[(size_t)((bn << 6) + d) * 1024 + i0 + cc * 8] = o;
  }
}

// ---------------- QKV GEMM (m97-style: BK=64, global_load_lds) ----------------
// LDS k-grouped As[g][r][8]; chunk c = g*128+r stored at byte c*16 (linear in c),
// staged via GLDS with per-lane permuted global source (r=c&127, g=c>>7).
__global__ __launch_bounds__(256) void gemm_qkv(const u16* __restrict__ A, const u16* __restrict__ Bw,
                                                const float* __restrict__ bias,
                                                u16* __restrict__ Qo, u16* __restrict__ Ko,
                                                u16* __restrict__ Vo) {
  __shared__ u16 As[8][128][8];   // 16 KB
  __shared__ u16 Bs[8][128][8];   // 16 KB
  const int m0 = blockIdx.y * 128, n0 = blockIdx.x * 128;
  const int t = threadIdx.x, lane = t & 63, w = t >> 6;
  const int wr = w >> 1, wc = w & 1;
  const int l16 = lane & 15, lg = lane >> 4;
  f32x4 acc[4][4] = {};

  for (int k0 = 0; k0 < 1024; k0 += 64) {
#pragma unroll
    for (int s = 0; s < 4; ++s) {
      int c = t + 256 * s;
      int r = c & 127, g = c >> 7;
      GLDS(&A[(size_t)(m0 + r) * 1024 + k0 + g * 8], &As[g][r][0]);
      GLDS(&Bw[(size_t)(n0 + r) * 1024 + k0 + g * 8], &Bs[g][r][0]);
    }
    __syncthreads();   // vmcnt drain + barrier: staged data visible
#pragma unroll
    for (int kk = 0; kk < 2; ++kk) {
      bf16x8 af[4], bfr[4];
#pragma unroll
      for (int m = 0; m < 4; ++m) af[m] = *(const bf16x8*)&As[lg + 4 * kk][wr * 64 + m * 16 + l16][0];
#pragma unroll
      for (int n = 0; n < 4; ++n) bfr[n] = *(const bf16x8*)&Bs[lg + 4 * kk][wc * 64 + n * 16 + l16][0];
#pragma unroll
      for (int m = 0; m < 4; ++m)
#pragma unroll
        for (int n = 0; n < 4; ++n) acc[m][n] = MFMA16(af[m], bfr[n], acc[m][n]);
    }
    __syncthreads();   // protect LDS before next iter's DMA writes
  }

#pragma unroll
  for (int n = 0; n < 4; ++n) {
    int col = n0 + wc * 64 + n * 16 + l16;
    float bq = bias[col];
    int which = col >> 10;          // 0=q 1=k 2=v
    int h = col & 1023;
    int head = h >> 6, d = h & 63;
    u16* dst = which == 0 ? Qo : (which == 1 ? Ko : Vo);
    float scale = which == 1 ? 0.125f : 1.0f;   // fold 1/sqrt(64) into K
#pragma unroll
    for (int m = 0; m < 4; ++m) {
#pragma unroll
      for (int r = 0; r < 4; ++r) {
        int row = m0 + wr * 64 + m * 16 + lg * 4 + r;
        int b = row >> 10, ii = row & 1023;
        float v = (acc[m][n][r] + bq) * scale;
        dst[(size_t)(((b * 16 + head) << 10) + ii) * 64 + d] = f2b(v);
      }
    }
  }
}

// ---------------- out = AO @ Wo^T + bo (m97-style) ----------------
__global__ __launch_bounds__(256) void gemm_out(const u16* __restrict__ A, const u16* __restrict__ Bw,
                                                const float* __restrict__ bias, float* __restrict__ Co) {
  __shared__ u16 As[8][128][8];
  __shared__ u16 Bs[8][128][8];
  const int m0 = blockIdx.y * 128, n0 = blockIdx.x * 128;
  const int t = threadIdx.x, lane = t & 63, w = t >> 6;
  const int wr = w >> 1, wc = w & 1;
  const int l16 = lane & 15, lg = lane >> 4;
  f32x4 acc[4][4] = {};

  for (int k0 = 0; k0 < 1024; k0 += 64) {
#pragma unroll
    for (int s = 0; s < 4; ++s) {
      int c = t + 256 * s;
      int r = c & 127, g = c >> 7;
      GLDS(&A[(size_t)(m0 + r) * 1024 + k0 + g * 8], &As[g][r][0]);
      GLDS(&Bw[(size_t)(n0 + r) * 1024 + k0 + g * 8], &Bs[g][r][0]);
    }
    __syncthreads();
#pragma unroll
    for (int kk = 0; kk < 2; ++kk) {
      bf16x8 af[4], bfr[4];
#pragma unroll
      for (int m = 0; m < 4; ++m) af[m] = *(const bf16x8*)&As[lg + 4 * kk][wr * 64 + m * 16 + l16][0];
#pragma unroll
      for (int n = 0; n < 4; ++n) bfr[n] = *(const bf16x8*)&Bs[lg + 4 * kk][wc * 64 + n * 16 + l16][0];
#pragma unroll
      for (int m = 0; m < 4; ++m)
#pragma unroll
        for (int n = 0; n < 4; ++n) acc[m][n] = MFMA16(af[m], bfr[n], acc[m][n]);
    }
    __syncthreads();
  }

#pragma unroll
  for (int n = 0; n < 4; ++n) {
    int col = n0 + wc * 64 + n * 16 + l16;
    float bq = bias[col];
#pragma unroll
    for (int m = 0; m < 4; ++m) {
#pragma unroll
      for (int r = 0; r < 4; ++r) {
        int row = m0 + wr * 64 + m * 16 + lg * 4 + r;
        Co[(size_t)row * 1024 + col] = acc[m][n][r] + bq;
      }
    }
  }
}

// ---------------- fused causal attention with relative bias ----------------
// grid (64 bn, 16 qtiles), 4 waves; wave w owns Q rows [16w,16w+16).
// T14 async-stage: next-tile K/V/F global->reg issued right after top barrier,
// ds_written at next loop head. Deferred row-sum butterfly (once, after loop).
__global__ __launch_bounds__(256) void attn_kernel(const u16* __restrict__ Qg, const u16* __restrict__ Kg,
                                                   const u16* __restrict__ Vtg, const u16* __restrict__ Fg,
                                                   u16* __restrict__ AO) {
  __shared__ u16 Kl[4096];          // [j][d] swz
  __shared__ u16 Vl[4096];          // [d][j] swz
  __shared__ u16 Fl[8192];          // [t][d] swz, t in [0,128)
  __shared__ u16 Bnd[4][16][84];    // per-wave band [i_local][c]
  __shared__ u16 Pl[4][1024];       // per-wave P [i_local][j] swz

  const int bn = blockIdx.x;
  const int b = bn >> 4, n = bn & 15;
  const int qt = 15 - (int)blockIdx.y;       // heavy tiles first
  const int i0 = qt * 64;
  const int t = threadIdx.x, lane = t & 63, w = t >> 6;
  const int l16 = lane & 15, lg = lane >> 4;

  // staging chunk ids (same for K/V and F slots)
  const int rr0 = t >> 3, cc0 = t & 7;                    // K/V s=0, F s=0
  const int rr1 = (t + 256) >> 3, cc1 = t & 7;            // K/V s=1, F s=1
  const int rr2 = (t + 512) >> 3, cc2 = t & 7;            // F s=2
  const int rr3 = (t + 768) >> 3, cc3 = t & 7;            // F s=3

  // Q strip fragments: row = l16, d = 8*lg + 32*kk
  bf16x8 qf[2];
  {
    const u16* qp = &Qg[(size_t)((bn << 10) + i0 + (w << 4) + l16) * 64 + lg * 8];
    qf[0] = *(const bf16x8*)qp;
    qf[1] = *(const bf16x8*)(qp + 32);
  }

  float mrun[4], lsum[4];
  f32x4 ao[4] = {};
#pragma unroll
  for (int r = 0; r < 4; ++r) { mrun[r] = -3.0e38f; lsum[r] = 0.0f; }

  u16x8 rk0, rk1, rv0, rv1, rf0, rf1, rf2, rf3;

#define LOAD_STAGE(jt_) do { \
    int j0_ = (jt_) * 64, mb_ = i0 - j0_ - 63; \
    rk0 = *(const u16x8*)&Kg[(size_t)((bn << 10) + j0_ + rr0) * 64 + cc0 * 8]; \
    rk1 = *(const u16x8*)&Kg[(size_t)((bn << 10) + j0_ + rr1) * 64 + cc1 * 8]; \
    rv0 = *(const u16x8*)&Vtg[(size_t)((bn << 6) + rr0) * 1024 + j0_ + cc0 * 8]; \
    rv1 = *(const u16x8*)&Vtg[(size_t)((bn << 6) + rr1) * 1024 + j0_ + cc1 * 8]; \
    int m0_ = mb_ + rr0; m0_ = m0_ < 0 ? 0 : (m0_ > 1023 ? 1023 : m0_); \
    int m1_ = mb_ + rr1; m1_ = m1_ < 0 ? 0 : (m1_ > 1023 ? 1023 : m1_); \
    int m2_ = mb_ + rr2; m2_ = m2_ < 0 ? 0 : (m2_ > 1023 ? 1023 : m2_); \
    int m3_ = mb_ + rr3; m3_ = m3_ < 0 ? 0 : (m3_ > 1023 ? 1023 : m3_); \
    rf0 = *(const u16x8*)&Fg[(size_t)((n << 10) + m0_) * 64 + cc0 * 8]; \
    rf1 = *(const u16x8*)&Fg[(size_t)((n << 10) + m1_) * 64 + cc1 * 8]; \
    rf2 = *(const u16x8*)&Fg[(size_t)((n << 10) + m2_) * 64 + cc2 * 8]; \
    rf3 = *(const u16x8*)&Fg[(size_t)((n << 10) + m3_) * 64 + cc3 * 8]; \
  } while (0)

  LOAD_STAGE(0);

  for (int jt = 0; jt <= qt; ++jt) {
    const bool diag = (jt == qt);

    // ---- write staged regs to LDS (swizzled) ----
    *(u16x8*)&Kl[rr0 * 64 + (((cc0 ^ (rr0 & 7)) & 7) << 3)] = rk0;
    *(u16x8*)&Kl[rr1 * 64 + (((cc1 ^ (rr1 & 7)) & 7) << 3)] = rk1;
    *(u16x8*)&Vl[rr0 * 64 + (((cc0 ^ (rr0 & 7)) & 7) << 3)] = rv0;
    *(u16x8*)&Vl[rr1 * 64 + (((cc1 ^ (rr1 & 7)) & 7) << 3)] = rv1;
    *(u16x8*)&Fl[rr0 * 64 + (((cc0 ^ (rr0 & 7)) & 7) << 3)] = rf0;
    *(u16x8*)&Fl[rr1 * 64 + (((cc1 ^ (rr1 & 7)) & 7) << 3)] = rf1;
    *(u16x8*)&Fl[rr2 * 64 + (((cc2 ^ (rr2 & 7)) & 7) << 3)] = rf2;
    *(u16x8*)&Fl[rr3 * 64 + (((cc3 ^ (rr3 & 7)) & 7) << 3)] = rf3;
    __syncthreads();

    // ---- T14: issue next-tile loads now; latency hides under compute ----
    if (jt < qt) LOAD_STAGE(jt + 1);

    // ---- QK^T ----
    f32x4 sc[4] = {};
#pragma unroll
    for (int kk = 0; kk < 2; ++kk)
#pragma unroll
      for (int nn = 0; nn < 4; ++nn) {
        int jr = nn * 16 + l16;
        bf16x8 kb = *(const bf16x8*)&Kl[jr * 64 + ((((lg + 4 * kk) ^ (jr & 7)) & 7) << 3)];
        sc[nn] = MFMA16(qf[kk], kb, sc[nn]);
      }
    // ---- band: per-wave 5 col-tiles, window t in [16w, 16w+80) ----
    f32x4 bb[5] = {};
#pragma unroll
    for (int kk = 0; kk < 2; ++kk)
#pragma unroll
      for (int ct = 0; ct < 5; ++ct) {
        int trow = (w << 4) + ct * 16 + l16;
        bf16x8 fb = *(const bf16x8*)&Fl[trow * 64 + ((((lg + 4 * kk) ^ (trow & 7)) & 7) << 3)];
        bb[ct] = MFMA16(qf[kk], fb, bb[ct]);
      }
#pragma unroll
    for (int ct = 0; ct < 5; ++ct)
#pragma unroll
      for (int r = 0; r < 4; ++r)
        Bnd[w][lg * 4 + r][ct * 16 + l16] = f2b(bb[ct][r]);
    WAVE_LDS_FENCE();   // Bnd wave-private: drain DS + compiler fence

    // ---- gather band, mask, online softmax (deferred sum butterfly) ----
    const unsigned* bw = (const unsigned*)&Bnd[w][0][0];
    float pv[4][4];
#pragma unroll
    for (int r = 0; r < 4; ++r) {
      int il = lg * 4 + r;
      int c0 = il - l16 + 63;               // in [48,78]
      int u0 = il * 84 + c0;
      int sh = (u0 & 1) << 4;
      float stmp[4];
      float mx = -3.0e38f;
#pragma unroll
      for (int nn = 0; nn < 4; ++nn) {
        unsigned dv = bw[(u0 >> 1) - 8 * nn];
        float s = sc[nn][r] + b2f((u16)((dv >> sh) & 0xffffu));
        if (diag && (c0 - 16 * nn + (w << 4) < 63)) s = -1.0e30f;   // j > i
        stmp[nn] = s;
        mx = fmaxf(mx, s);
      }
#pragma unroll
      for (int off = 1; off < 16; off <<= 1) mx = fmaxf(mx, __shfl_xor(mx, off));
      float mnew = fmaxf(mrun[r], mx);
      float scl = __expf(mrun[r] - mnew);
      float rs = 0.0f;
#pragma unroll
      for (int nn = 0; nn < 4; ++nn) {
        pv[nn][r] = __expf(stmp[nn] - mnew);
        rs += pv[nn][r];
      }
      lsum[r] = lsum[r] * scl + rs;    // per-lane partial; butterfly at end
      mrun[r] = mnew;
#pragma unroll
      for (int nd = 0; nd < 4; ++nd) ao[nd][r] *= scl;
    }

    // ---- P -> LDS (swizzled row-major), PV ----
#pragma unroll
    for (int nn = 0; nn < 4; ++nn)
#pragma unroll
      for (int r = 0; r < 4; ++r) {
        int i = lg * 4 + r, j = nn * 16 + l16;
        Pl[w][i * 64 + ((((j >> 3) ^ (i & 7)) & 7) << 3) + (j & 7)] = f2b(pv[nn][r]);
      }
    WAVE_LDS_FENCE();   // Pl wave-private
#pragma unroll
    for (int kk = 0; kk < 2; ++kk) {
      bf16x8 pa = *(const bf16x8*)&Pl[w][l16 * 64 + ((((lg + 4 * kk) ^ (l16 & 7)) & 7) << 3)];
#pragma unroll
      for (int nd = 0; nd < 4; ++nd) {
        int dr = nd * 16 + l16;
        bf16x8 vb = *(const bf16x8*)&Vl[dr * 64 + ((((lg + 4 * kk) ^ (dr & 7)) & 7) << 3)];
        ao[nd] = MFMA16(pa, vb, ao[nd]);
      }
    }
    __syncthreads();   // protect Kl/Vl/Fl for next iteration
  }

  // ---- finalize row sums, normalize + write ----
#pragma unroll
  for (int r = 0; r < 4; ++r)
#pragma unroll
    for (int off = 1; off < 16; off <<= 1) lsum[r] += __shfl_xor(lsum[r], off);

#pragma unroll
  for (int nd = 0; nd < 4; ++nd)
#pragma unroll
    for (int r = 0; r < 4; ++r) {
      int i = i0 + (w << 4) + lg * 4 + r;
      int d = nd * 16 + l16;
      float v = ao[nd][r] / lsum[r];
      AO[(size_t)((b << 10) + i) * 1024 + n * 64 + d] = f2b(v);
    }
#undef LOAD_STAGE
}

// ---------------- launch ----------------
extern "C" void kernel_launch(void* const* d_in, const int* in_sizes, int n_in,
                              void* d_out, int out_size, void* d_ws, size_t ws_size,
                              hipStream_t stream) {
  (void)in_sizes; (void)n_in; (void)out_size; (void)ws_size;
  const float* x    = (const float*)d_in[0];
  // d_in[1] = mask: always causal triu(k=1) -> analytic
  const float* Wqkv = (const float*)d_in[2];
  const float* bqkv = (const float*)d_in[3];
  const float* Wo   = (const float*)d_in[4];
  const float* bo   = (const float*)d_in[5];
  const float* Er   = (const float*)d_in[6];
  float* out = (float*)d_out;

  char* p = (char*)d_ws;
  u16* xb    = (u16*)p; p += (size_t)4096 * 1024 * 2;
  u16* wqkvb = (u16*)p; p += (size_t)3072 * 1024 * 2;
  u16* wob   = (u16*)p; p += (size_t)1024 * 1024 * 2;
  u16* Fb    = (u16*)p; p += (size_t)16 * 1024 * 64 * 2;
  u16* Qb    = (u16*)p; p += (size_t)64 * 1024 * 64 * 2;
  u16* Kb    = (u16*)p; p += (size_t)64 * 1024 * 64 * 2;
  u16* Vb    = (u16*)p; p += (size_t)64 * 1024 * 64 * 2;
  u16* Vtb   = (u16*)p; p += (size_t)64 * 1024 * 64 * 2;   // V^T (bn, d, i)
  u16* AO    = (u16*)p; p += (size_t)4096 * 1024 * 2;

  cvt_bf16<<<4096, 256, 0, stream>>>(x, xb, 1048576);
  cvt_bf16<<<3072, 256, 0, stream>>>(Wqkv, wqkvb, 786432);
  cvt_bf16<<<1024, 256, 0, stream>>>(Wo, wob, 262144);
  build_F<<<1024, 256, 0, stream>>>(Er, Fb);
  gemm_qkv<<<dim3(24, 32), 256, 0, stream>>>(xb, wqkvb, bqkv, Qb, Kb, Vb);
  transpose_v<<<dim3(64, 16), 256, 0, stream>>>(Vb, Vtb);
  attn_kernel<<<dim3(64, 16), 256, 0, stream>>>(Qb, Kb, Vtb, Fb, AO);
  gemm_out<<<dim3(8, 32), 256, 0, stream>>>(AO, wob, bo, out);
}

// Round 5
// 166.174 us; speedup vs baseline: 1.0503x; 1.0503x over previous
//
#include <hip/hip_runtime.h>

typedef unsigned short u16;
typedef __bf16 bf16x8 __attribute__((ext_vector_type(8)));
typedef unsigned short u16x8 __attribute__((ext_vector_type(8)));
typedef float f32x4 __attribute__((ext_vector_type(4)));

#define MFMA16(a, b, c) __builtin_amdgcn_mfma_f32_16x16x32_bf16((a), (b), (c), 0, 0, 0)

// same-wave LDS write->read fence: drain DS queue + block compiler reordering
#define WAVE_LDS_FENCE() do { \
  asm volatile("s_waitcnt lgkmcnt(0)" ::: "memory"); \
  __builtin_amdgcn_sched_barrier(0); \
} while (0)

// end-of-phase: drain async stages, full block barrier (no forced lgkm beyond reg deps)
#define PHASE_BARRIER() do { \
  asm volatile("s_waitcnt vmcnt(0)" ::: "memory"); \
  __builtin_amdgcn_sched_barrier(0); \
  __builtin_amdgcn_s_barrier(); \
} while (0)

// async global->LDS DMA, 16B per lane; LDS dest must be uniform base + lane*16
#define GLDS(gp, lp) __builtin_amdgcn_global_load_lds( \
    (const __attribute__((address_space(1))) unsigned int*)(gp), \
    (__attribute__((address_space(3))) unsigned int*)(lp), 16, 0, 0)

__device__ __forceinline__ u16 f2b(float f) {
  unsigned u = __float_as_uint(f);
  u += 0x7fffu + ((u >> 16) & 1u);   // RNE; inputs finite
  return (u16)(u >> 16);
}
__device__ __forceinline__ float b2f(u16 h) {
  return __uint_as_float(((unsigned)h) << 16);
}

// ---------------- fused converts (x, Wqkv, Wo) ----------------
__global__ void cvt_all(const float* __restrict__ x, u16* __restrict__ xb,
                        const float* __restrict__ w1, u16* __restrict__ w1b,
                        const float* __restrict__ w2, u16* __restrict__ w2b) {
  int i = blockIdx.x * blockDim.x + threadIdx.x;   // float4 chunk id, < 2097152
  const float* s; u16* d; int off;
  if (i < 1048576)      { s = x;  d = xb;  off = i; }
  else if (i < 1835008) { s = w1; d = w1b; off = i - 1048576; }
  else                  { s = w2; d = w2b; off = i - 1835008; }
  float4 v = *(const float4*)(s + (size_t)off * 4);
  *(ushort4*)(d + (size_t)off * 4) = make_ushort4(f2b(v.x), f2b(v.y), f2b(v.z), f2b(v.w));
}

// F[n][m][d] = Er[n][(2048 - m) % 2048][d]
__global__ void build_F(const float* __restrict__ Er, u16* __restrict__ Fb) {
  int i = blockIdx.x * blockDim.x + threadIdx.x;
  int base = i * 4;
  int d = base & 63;
  int m = (base >> 6) & 1023;
  int n = base >> 16;
  int sm = (2048 - m) & 2047;
  float4 v = *(const float4*)(Er + ((size_t)(n * 2048 + sm) * 64 + d));
  *(ushort4*)(Fb + (size_t)base) = make_ushort4(f2b(v.x), f2b(v.y), f2b(v.z), f2b(v.w));
}

// ---------------- V transpose: V[bn][i][d] -> Vt[bn][d][i] ----------------
__global__ __launch_bounds__(256) void transpose_v(const u16* __restrict__ V, u16* __restrict__ Vt) {
  __shared__ u16 T[4096];
  const int bn = blockIdx.x, i0 = blockIdx.y * 64;
  const int t = threadIdx.x;
#pragma unroll
  for (int s = 0; s < 2; ++s) {
    int ch = t + 256 * s;
    int i = ch >> 3, c = ch & 7;
    u16x8 v = *(const u16x8*)&V[(size_t)((bn << 10) + i0 + i) * 64 + c * 8];
#pragma unroll
    for (int e = 0; e < 8; ++e) {
      int d = c * 8 + e;
      T[d * 64 + ((((i >> 3) ^ (d & 7) ^ ((d >> 3) & 7)) & 7) << 3) + (i & 7)] = v[e];
    }
  }
  __syncthreads();
#pragma unroll
  for (int s = 0; s < 2; ++s) {
    int ch = t + 256 * s;
    int d = ch >> 3, cc = ch & 7;
    u16x8 o = *(const u16x8*)&T[d * 64 + (((cc ^ (d & 7) ^ ((d >> 3) & 7)) & 7) << 3)];
    *(u16x8*)&Vt[(size_t)((bn << 6) + d) * 1024 + i0 + cc * 8] = o;
  }
}

// ---------------- QKV GEMM: 2-phase double-buffered GLDS, BK=32 ----------------
// STAGE(next) issued at iteration top -> full MFMA phase of latency slack;
// single vmcnt(0)+s_barrier per K-step (catalog T3 "minimum 2-phase").
__global__ __launch_bounds__(256) void gemm_qkv(const u16* __restrict__ A, const u16* __restrict__ Bw,
                                                const float* __restrict__ bias,
                                                u16* __restrict__ Qo, u16* __restrict__ Ko,
                                                u16* __restrict__ Vo) {
  __shared__ u16 As[2][4][128][8];   // [buf][kg][row][8] = 8 KB/buf
  __shared__ u16 Bs[2][4][128][8];
  const int m0 = blockIdx.y * 128, n0 = blockIdx.x * 128;
  const int t = threadIdx.x, lane = t & 63, w = t >> 6;
  const int wr = w >> 1, wc = w & 1;
  const int l16 = lane & 15, lg = lane >> 4;
  f32x4 acc[4][4] = {};
  const int c0 = t, r0 = c0 & 127, g0 = c0 >> 7;          // chunks 0..255
  const int c1 = t + 256, r1 = c1 & 127, g1 = c1 >> 7;    // chunks 256..511

#define STAGE(buf, k0) do { \
    GLDS(&A[(size_t)(m0 + r0) * 1024 + (k0) + g0 * 8], &As[buf][g0][r0][0]); \
    GLDS(&A[(size_t)(m0 + r1) * 1024 + (k0) + g1 * 8], &As[buf][g1][r1][0]); \
    GLDS(&Bw[(size_t)(n0 + r0) * 1024 + (k0) + g0 * 8], &Bs[buf][g0][r0][0]); \
    GLDS(&Bw[(size_t)(n0 + r1) * 1024 + (k0) + g1 * 8], &Bs[buf][g1][r1][0]); \
  } while (0)

  STAGE(0, 0);
  PHASE_BARRIER();

#pragma unroll 2
  for (int kt = 0; kt < 32; ++kt) {
    const int buf = kt & 1;
    if (kt < 31) STAGE(buf ^ 1, (kt + 1) * 32);
    __builtin_amdgcn_sched_barrier(0);      // keep stage issue ahead of compute
    bf16x8 af[4], bfr[4];
#pragma unroll
    for (int m = 0; m < 4; ++m) af[m] = *(const bf16x8*)&As[buf][lg][wr * 64 + m * 16 + l16][0];
#pragma unroll
    for (int n = 0; n < 4; ++n) bfr[n] = *(const bf16x8*)&Bs[buf][lg][wc * 64 + n * 16 + l16][0];
#pragma unroll
    for (int m = 0; m < 4; ++m)
#pragma unroll
      for (int n = 0; n < 4; ++n) acc[m][n] = MFMA16(af[m], bfr[n], acc[m][n]);
    PHASE_BARRIER();
  }
#undef STAGE

#pragma unroll
  for (int n = 0; n < 4; ++n) {
    int col = n0 + wc * 64 + n * 16 + l16;
    float bq = bias[col];
    int which = col >> 10;          // 0=q 1=k 2=v
    int h = col & 1023;
    int head = h >> 6, d = h & 63;
    u16* dst = which == 0 ? Qo : (which == 1 ? Ko : Vo);
    float scale = which == 1 ? 0.125f : 1.0f;   // fold 1/sqrt(64) into K
#pragma unroll
    for (int m = 0; m < 4; ++m) {
#pragma unroll
      for (int r = 0; r < 4; ++r) {
        int row = m0 + wr * 64 + m * 16 + lg * 4 + r;
        int b = row >> 10, ii = row & 1023;
        float v = (acc[m][n][r] + bq) * scale;
        dst[(size_t)(((b * 16 + head) << 10) + ii) * 64 + d] = f2b(v);
      }
    }
  }
}

// ---------------- out = AO @ Wo^T + bo: 2-phase double-buffered GLDS ----------------
__global__ __launch_bounds__(256) void gemm_out(const u16* __restrict__ A, const u16* __restrict__ Bw,
                                                const float* __restrict__ bias, float* __restrict__ Co) {
  __shared__ u16 As[2][4][128][8];
  __shared__ u16 Bs[2][4][128][8];
  const int m0 = blockIdx.y * 128, n0 = blockIdx.x * 128;
  const int t = threadIdx.x, lane = t & 63, w = t >> 6;
  const int wr = w >> 1, wc = w & 1;
  const int l16 = lane & 15, lg = lane >> 4;
  f32x4 acc[4][4] = {};
  const int c0 = t, r0 = c0 & 127, g0 = c0 >> 7;
  const int c1 = t + 256, r1 = c1 & 127, g1 = c1 >> 7;

#define STAGE(buf, k0) do { \
    GLDS(&A[(size_t)(m0 + r0) * 1024 + (k0) + g0 * 8], &As[buf][g0][r0][0]); \
    GLDS(&A[(size_t)(m0 + r1) * 1024 + (k0) + g1 * 8], &As[buf][g1][r1][0]); \
    GLDS(&Bw[(size_t)(n0 + r0) * 1024 + (k0) + g0 * 8], &Bs[buf][g0][r0][0]); \
    GLDS(&Bw[(size_t)(n0 + r1) * 1024 + (k0) + g1 * 8], &Bs[buf][g1][r1][0]); \
  } while (0)

  STAGE(0, 0);
  PHASE_BARRIER();

#pragma unroll 2
  for (int kt = 0; kt < 32; ++kt) {
    const int buf = kt & 1;
    if (kt < 31) STAGE(buf ^ 1, (kt + 1) * 32);
    __builtin_amdgcn_sched_barrier(0);
    bf16x8 af[4], bfr[4];
#pragma unroll
    for (int m = 0; m < 4; ++m) af[m] = *(const bf16x8*)&As[buf][lg][wr * 64 + m * 16 + l16][0];
#pragma unroll
    for (int n = 0; n < 4; ++n) bfr[n] = *(const bf16x8*)&Bs[buf][lg][wc * 64 + n * 16 + l16][0];
#pragma unroll
    for (int m = 0; m < 4; ++m)
#pragma unroll
      for (int n = 0; n < 4; ++n) acc[m][n] = MFMA16(af[m], bfr[n], acc[m][n]);
    PHASE_BARRIER();
  }
#undef STAGE

#pragma unroll
  for (int n = 0; n < 4; ++n) {
    int col = n0 + wc * 64 + n * 16 + l16;
    float bq = bias[col];
#pragma unroll
    for (int m = 0; m < 4; ++m) {
#pragma unroll
      for (int r = 0; r < 4; ++r) {
        int row = m0 + wr * 64 + m * 16 + lg * 4 + r;
        Co[(size_t)row * 1024 + col] = acc[m][n][r] + bq;
      }
    }
  }
}

// ---------------- fused causal attention with relative bias (unchanged from R4) ----------------
__global__ __launch_bounds__(256) void attn_kernel(const u16* __restrict__ Qg, const u16* __restrict__ Kg,
                                                   const u16* __restrict__ Vtg, const u16* __restrict__ Fg,
                                                   u16* __restrict__ AO) {
  __shared__ u16 Kl[4096];          // [j][d] swz
  __shared__ u16 Vl[4096];          // [d][j] swz
  __shared__ u16 Fl[8192];          // [t][d] swz, t in [0,128)
  __shared__ u16 Bnd[4][16][84];    // per-wave band [i_local][c]
  __shared__ u16 Pl[4][1024];       // per-wave P [i_local][j] swz

  const int bn = blockIdx.x;
  const int b = bn >> 4, n = bn & 15;
  const int qt = 15 - (int)blockIdx.y;       // heavy tiles first
  const int i0 = qt * 64;
  const int t = threadIdx.x, lane = t & 63, w = t >> 6;
  const int l16 = lane & 15, lg = lane >> 4;

  const int rr0 = t >> 3, cc0 = t & 7;
  const int rr1 = (t + 256) >> 3, cc1 = t & 7;
  const int rr2 = (t + 512) >> 3, cc2 = t & 7;
  const int rr3 = (t + 768) >> 3, cc3 = t & 7;

  bf16x8 qf[2];
  {
    const u16* qp = &Qg[(size_t)((bn << 10) + i0 + (w << 4) + l16) * 64 + lg * 8];
    qf[0] = *(const bf16x8*)qp;
    qf[1] = *(const bf16x8*)(qp + 32);
  }

  float mrun[4], lsum[4];
  f32x4 ao[4] = {};
#pragma unroll
  for (int r = 0; r < 4; ++r) { mrun[r] = -3.0e38f; lsum[r] = 0.0f; }

  u16x8 rk0, rk1, rv0, rv1, rf0, rf1, rf2, rf3;

#define LOAD_STAGE(jt_) do { \
    int j0_ = (jt_) * 64, mb_ = i0 - j0_ - 63; \
    rk0 = *(const u16x8*)&Kg[(size_t)((bn << 10) + j0_ + rr0) * 64 + cc0 * 8]; \
    rk1 = *(const u16x8*)&Kg[(size_t)((bn << 10) + j0_ + rr1) * 64 + cc1 * 8]; \
    rv0 = *(const u16x8*)&Vtg[(size_t)((bn << 6) + rr0) * 1024 + j0_ + cc0 * 8]; \
    rv1 = *(const u16x8*)&Vtg[(size_t)((bn << 6) + rr1) * 1024 + j0_ + cc1 * 8]; \
    int m0_ = mb_ + rr0; m0_ = m0_ < 0 ? 0 : (m0_ > 1023 ? 1023 : m0_); \
    int m1_ = mb_ + rr1; m1_ = m1_ < 0 ? 0 : (m1_ > 1023 ? 1023 : m1_); \
    int m2_ = mb_ + rr2; m2_ = m2_ < 0 ? 0 : (m2_ > 1023 ? 1023 : m2_); \
    int m3_ = mb_ + rr3; m3_ = m3_ < 0 ? 0 : (m3_ > 1023 ? 1023 : m3_); \
    rf0 = *(const u16x8*)&Fg[(size_t)((n << 10) + m0_) * 64 + cc0 * 8]; \
    rf1 = *(const u16x8*)&Fg[(size_t)((n << 10) + m1_) * 64 + cc1 * 8]; \
    rf2 = *(const u16x8*)&Fg[(size_t)((n << 10) + m2_) * 64 + cc2 * 8]; \
    rf3 = *(const u16x8*)&Fg[(size_t)((n << 10) + m3_) * 64 + cc3 * 8]; \
  } while (0)

  LOAD_STAGE(0);

  for (int jt = 0; jt <= qt; ++jt) {
    const bool diag = (jt == qt);

    *(u16x8*)&Kl[rr0 * 64 + (((cc0 ^ (rr0 & 7)) & 7) << 3)] = rk0;
    *(u16x8*)&Kl[rr1 * 64 + (((cc1 ^ (rr1 & 7)) & 7) << 3)] = rk1;
    *(u16x8*)&Vl[rr0 * 64 + (((cc0 ^ (rr0 & 7)) & 7) << 3)] = rv0;
    *(u16x8*)&Vl[rr1 * 64 + (((cc1 ^ (rr1 & 7)) & 7) << 3)] = rv1;
    *(u16x8*)&Fl[rr0 * 64 + (((cc0 ^ (rr0 & 7)) & 7) << 3)] = rf0;
    *(u16x8*)&Fl[rr1 * 64 + (((cc1 ^ (rr1 & 7)) & 7) << 3)] = rf1;
    *(u16x8*)&Fl[rr2 * 64 + (((cc2 ^ (rr2 & 7)) & 7) << 3)] = rf2;
    *(u16x8*)&Fl[rr3 * 64 + (((cc3 ^ (rr3 & 7)) & 7) << 3)] = rf3;
    __syncthreads();

    if (jt < qt) LOAD_STAGE(jt + 1);   // T14: issue early, consumed next iter

    // ---- QK^T ----
    f32x4 sc[4] = {};
#pragma unroll
    for (int kk = 0; kk < 2; ++kk)
#pragma unroll
      for (int nn = 0; nn < 4; ++nn) {
        int jr = nn * 16 + l16;
        bf16x8 kb = *(const bf16x8*)&Kl[jr * 64 + ((((lg + 4 * kk) ^ (jr & 7)) & 7) << 3)];
        sc[nn] = MFMA16(qf[kk], kb, sc[nn]);
      }
    // ---- band: per-wave 5 col-tiles, window t in [16w, 16w+80) ----
    f32x4 bb[5] = {};
#pragma unroll
    for (int kk = 0; kk < 2; ++kk)
#pragma unroll
      for (int ct = 0; ct < 5; ++ct) {
        int trow = (w << 4) + ct * 16 + l16;
        bf16x8 fb = *(const bf16x8*)&Fl[trow * 64 + ((((lg + 4 * kk) ^ (trow & 7)) & 7) << 3)];
        bb[ct] = MFMA16(qf[kk], fb, bb[ct]);
      }
#pragma unroll
    for (int ct = 0; ct < 5; ++ct)
#pragma unroll
      for (int r = 0; r < 4; ++r)
        Bnd[w][lg * 4 + r][ct * 16 + l16] = f2b(bb[ct][r]);
    WAVE_LDS_FENCE();

    // ---- gather band, mask, online softmax (deferred sum butterfly) ----
    const unsigned* bw = (const unsigned*)&Bnd[w][0][0];
    float pv[4][4];
#pragma unroll
    for (int r = 0; r < 4; ++r) {
      int il = lg * 4 + r;
      int c0 = il - l16 + 63;
      int u0 = il * 84 + c0;
      int sh = (u0 & 1) << 4;
      float stmp[4];
      float mx = -3.0e38f;
#pragma unroll
      for (int nn = 0; nn < 4; ++nn) {
        unsigned dv = bw[(u0 >> 1) - 8 * nn];
        float s = sc[nn][r] + b2f((u16)((dv >> sh) & 0xffffu));
        if (diag && (c0 - 16 * nn + (w << 4) < 63)) s = -1.0e30f;
        stmp[nn] = s;
        mx = fmaxf(mx, s);
      }
#pragma unroll
      for (int off = 1; off < 16; off <<= 1) mx = fmaxf(mx, __shfl_xor(mx, off));
      float mnew = fmaxf(mrun[r], mx);
      float scl = __expf(mrun[r] - mnew);
      float rs = 0.0f;
#pragma unroll
      for (int nn = 0; nn < 4; ++nn) {
        pv[nn][r] = __expf(stmp[nn] - mnew);
        rs += pv[nn][r];
      }
      lsum[r] = lsum[r] * scl + rs;
      mrun[r] = mnew;
#pragma unroll
      for (int nd = 0; nd < 4; ++nd) ao[nd][r] *= scl;
    }

    // ---- P -> LDS (swizzled row-major), PV ----
#pragma unroll
    for (int nn = 0; nn < 4; ++nn)
#pragma unroll
      for (int r = 0; r < 4; ++r) {
        int i = lg * 4 + r, j = nn * 16 + l16;
        Pl[w][i * 64 + ((((j >> 3) ^ (i & 7)) & 7) << 3) + (j & 7)] = f2b(pv[nn][r]);
      }
    WAVE_LDS_FENCE();
#pragma unroll
    for (int kk = 0; kk < 2; ++kk) {
      bf16x8 pa = *(const bf16x8*)&Pl[w][l16 * 64 + ((((lg + 4 * kk) ^ (l16 & 7)) & 7) << 3)];
#pragma unroll
      for (int nd = 0; nd < 4; ++nd) {
        int dr = nd * 16 + l16;
        bf16x8 vb = *(const bf16x8*)&Vl[dr * 64 + ((((lg + 4 * kk) ^ (dr & 7)) & 7) << 3)];
        ao[nd] = MFMA16(pa, vb, ao[nd]);
      }
    }
    __syncthreads();
  }

#pragma unroll
  for (int r = 0; r < 4; ++r)
#pragma unroll
    for (int off = 1; off < 16; off <<= 1) lsum[r] += __shfl_xor(lsum[r], off);

#pragma unroll
  for (int nd = 0; nd < 4; ++nd)
#pragma unroll
    for (int r = 0; r < 4; ++r) {
      int i = i0 + (w << 4) + lg * 4 + r;
      int d = nd * 16 + l16;
      float v = ao[nd][r] / lsum[r];
      AO[(size_t)((b << 10) + i) * 1024 + n * 64 + d] = f2b(v);
    }
#undef LOAD_STAGE
}

// ---------------- launch ----------------
extern "C" void kernel_launch(void* const* d_in, const int* in_sizes, int n_in,
                              void* d_out, int out_size, void* d_ws, size_t ws_size,
                              hipStream_t stream) {
  (void)in_sizes; (void)n_in; (void)out_size; (void)ws_size;
  const float* x    = (const float*)d_in[0];
  // d_in[1] = mask: always causal triu(k=1) -> analytic
  const float* Wqkv = (const float*)d_in[2];
  const float* bqkv = (const float*)d_in[3];
  const float* Wo   = (const float*)d_in[4];
  const float* bo   = (const float*)d_in[5];
  const float* Er   = (const float*)d_in[6];
  float* out = (float*)d_out;

  char* p = (char*)d_ws;
  u16* xb    = (u16*)p; p += (size_t)4096 * 1024 * 2;
  u16* wqkvb = (u16*)p; p += (size_t)3072 * 1024 * 2;
  u16* wob   = (u16*)p; p += (size_t)1024 * 1024 * 2;
  u16* Fb    = (u16*)p; p += (size_t)16 * 1024 * 64 * 2;
  u16* Qb    = (u16*)p; p += (size_t)64 * 1024 * 64 * 2;
  u16* Kb    = (u16*)p; p += (size_t)64 * 1024 * 64 * 2;
  u16* Vb    = (u16*)p; p += (size_t)64 * 1024 * 64 * 2;
  u16* Vtb   = (u16*)p; p += (size_t)64 * 1024 * 64 * 2;   // V^T (bn, d, i)
  u16* AO    = (u16*)p; p += (size_t)4096 * 1024 * 2;

  cvt_all<<<8192, 256, 0, stream>>>(x, xb, Wqkv, wqkvb, Wo, wob);
  build_F<<<1024, 256, 0, stream>>>(Er, Fb);
  gemm_qkv<<<dim3(24, 32), 256, 0, stream>>>(xb, wqkvb, bqkv, Qb, Kb, Vb);
  transpose_v<<<dim3(64, 16), 256, 0, stream>>>(Vb, Vtb);
  attn_kernel<<<dim3(64, 16), 256, 0, stream>>>(Qb, Kb, Vtb, Fb, AO);
  gemm_out<<<dim3(8, 32), 256, 0, stream>>>(AO, wob, bo, out);
}

// Round 6
// 153.029 us; speedup vs baseline: 1.1405x; 1.0859x over previous
//
#include <hip/hip_runtime.h>

typedef unsigned short u16;
typedef __bf16 bf16x8 __attribute__((ext_vector_type(8)));
typedef unsigned short u16x8 __attribute__((ext_vector_type(8)));
typedef unsigned short u16x4 __attribute__((ext_vector_type(4)));
typedef float f32x4 __attribute__((ext_vector_type(4)));

#define MFMA16(a, b, c) __builtin_amdgcn_mfma_f32_16x16x32_bf16((a), (b), (c), 0, 0, 0)

// same-wave LDS write->read fence: drain DS queue + block compiler reordering
#define WAVE_LDS_FENCE() do { \
  asm volatile("s_waitcnt lgkmcnt(0)" ::: "memory"); \
  __builtin_amdgcn_sched_barrier(0); \
} while (0)

// counted-vmcnt pipeline barrier: wait only the OLDEST stage (keep N in flight)
#define PIPE_WAIT(N) do { \
  asm volatile("s_waitcnt vmcnt(" #N ")" ::: "memory"); \
  __builtin_amdgcn_sched_barrier(0); \
  __builtin_amdgcn_s_barrier(); \
  __builtin_amdgcn_sched_barrier(0); \
} while (0)

// async global->LDS DMA, 16B per lane; LDS dest must be uniform base + lane*16
#define GLDS(gp, lp) __builtin_amdgcn_global_load_lds( \
    (const __attribute__((address_space(1))) unsigned int*)(gp), \
    (__attribute__((address_space(3))) unsigned int*)(lp), 16, 0, 0)

__device__ __forceinline__ u16 f2b(float f) {
  unsigned u = __float_as_uint(f);
  u += 0x7fffu + ((u >> 16) & 1u);   // RNE; inputs finite
  return (u16)(u >> 16);
}
__device__ __forceinline__ float b2f(u16 h) {
  return __uint_as_float(((unsigned)h) << 16);
}

// ---------------- fused converts (x, Wqkv, Wo) ----------------
__global__ void cvt_all(const float* __restrict__ x, u16* __restrict__ xb,
                        const float* __restrict__ w1, u16* __restrict__ w1b,
                        const float* __restrict__ w2, u16* __restrict__ w2b) {
  int i = blockIdx.x * blockDim.x + threadIdx.x;
  const float* s; u16* d; int off;
  if (i < 1048576)      { s = x;  d = xb;  off = i; }
  else if (i < 1835008) { s = w1; d = w1b; off = i - 1048576; }
  else                  { s = w2; d = w2b; off = i - 1835008; }
  float4 v = *(const float4*)(s + (size_t)off * 4);
  *(ushort4*)(d + (size_t)off * 4) = make_ushort4(f2b(v.x), f2b(v.y), f2b(v.z), f2b(v.w));
}

// F[n][m][d] = Er[n][(2048 - m) % 2048][d]
__global__ void build_F(const float* __restrict__ Er, u16* __restrict__ Fb) {
  int i = blockIdx.x * blockDim.x + threadIdx.x;
  int base = i * 4;
  int d = base & 63;
  int m = (base >> 6) & 1023;
  int n = base >> 16;
  int sm = (2048 - m) & 2047;
  float4 v = *(const float4*)(Er + ((size_t)(n * 2048 + sm) * 64 + d));
  *(ushort4*)(Fb + (size_t)base) = make_ushort4(f2b(v.x), f2b(v.y), f2b(v.z), f2b(v.w));
}

// ---------------- V transpose: V[bn][i][d] -> Vt[bn][d][i] ----------------
__global__ __launch_bounds__(256) void transpose_v(const u16* __restrict__ V, u16* __restrict__ Vt) {
  __shared__ u16 T[4096];
  const int bn = blockIdx.x, i0 = blockIdx.y * 64;
  const int t = threadIdx.x;
#pragma unroll
  for (int s = 0; s < 2; ++s) {
    int ch = t + 256 * s;
    int i = ch >> 3, c = ch & 7;
    u16x8 v = *(const u16x8*)&V[(size_t)((bn << 10) + i0 + i) * 64 + c * 8];
#pragma unroll
    for (int e = 0; e < 8; ++e) {
      int d = c * 8 + e;
      T[d * 64 + ((((i >> 3) ^ (d & 7) ^ ((d >> 3) & 7)) & 7) << 3) + (i & 7)] = v[e];
    }
  }
  __syncthreads();
#pragma unroll
  for (int s = 0; s < 2; ++s) {
    int ch = t + 256 * s;
    int d = ch >> 3, cc = ch & 7;
    u16x8 o = *(const u16x8*)&T[d * 64 + (((cc ^ (d & 7) ^ ((d >> 3) & 7)) & 7) << 3)];
    *(u16x8*)&Vt[(size_t)((bn << 6) + d) * 1024 + i0 + cc * 8] = o;
  }
}

// ---------------- QKV GEMM: 3-buf counted-vmcnt pipeline, BK=32 ----------------
// Per iter: vmcnt(4) waits oldest stage only -> barrier -> issue STAGE(kt+2) -> compute.
// Prefetch distance ~2 iterations. XCD 2D region swizzle (8m x 12n tiles / XCD).
__global__ __launch_bounds__(256) void gemm_qkv(const u16* __restrict__ A, const u16* __restrict__ Bw,
                                                const float* __restrict__ bias,
                                                u16* __restrict__ Qo, u16* __restrict__ Ko,
                                                u16* __restrict__ Vo) {
  __shared__ u16 As[3][4][128][8];   // 16 KB/buf
  __shared__ u16 Bs[3][4][128][8];
  const int orig = blockIdx.y * 24 + blockIdx.x;   // gridDim = (24, 32)
  const int xcd = orig & 7, q = orig >> 3;         // 96 blocks/XCD
  const int mt = ((xcd >> 1) << 3) + q / 12;       // 4 m-bands of 8
  const int nt = (xcd & 1) * 12 + q % 12;          // 2 n-bands of 12
  const int m0 = mt * 128, n0 = nt * 128;
  const int t = threadIdx.x, lane = t & 63, w = t >> 6;
  const int wr = w >> 1, wc = w & 1;
  const int l16 = lane & 15, lg = lane >> 4;
  f32x4 acc[4][4] = {};
  const int r0 = t & 127, g0 = t >> 7;             // chunks 0..255
  const int g1 = g0 + 2;                           // chunks 256..511 (same row)

#define STAGE(buf, k0) do { \
    GLDS(&A[(size_t)(m0 + r0) * 1024 + (k0) + g0 * 8], &As[buf][g0][r0][0]); \
    GLDS(&A[(size_t)(m0 + r0) * 1024 + (k0) + g1 * 8], &As[buf][g1][r0][0]); \
    GLDS(&Bw[(size_t)(n0 + r0) * 1024 + (k0) + g0 * 8], &Bs[buf][g0][r0][0]); \
    GLDS(&Bw[(size_t)(n0 + r0) * 1024 + (k0) + g1 * 8], &Bs[buf][g1][r0][0]); \
  } while (0)

  STAGE(0, 0);
  STAGE(1, 32);

  int buf = 0;
  for (int kt = 0; kt < 32; ++kt) {
    if (kt < 31) PIPE_WAIT(4); else PIPE_WAIT(0);   // stage kt ready; kt+1 stays in flight
    if (kt < 30) {
      int nb = buf + 2; if (nb >= 3) nb -= 3;
      STAGE(nb, (kt + 2) * 32);
      __builtin_amdgcn_sched_barrier(0);
    }
    bf16x8 af[4], bfr[4];
#pragma unroll
    for (int m = 0; m < 4; ++m) af[m] = *(const bf16x8*)&As[buf][lg][wr * 64 + m * 16 + l16][0];
#pragma unroll
    for (int n = 0; n < 4; ++n) bfr[n] = *(const bf16x8*)&Bs[buf][lg][wc * 64 + n * 16 + l16][0];
#pragma unroll
    for (int m = 0; m < 4; ++m)
#pragma unroll
      for (int n = 0; n < 4; ++n) acc[m][n] = MFMA16(af[m], bfr[n], acc[m][n]);
    if (++buf == 3) buf = 0;
  }
#undef STAGE

#pragma unroll
  for (int n = 0; n < 4; ++n) {
    int col = n0 + wc * 64 + n * 16 + l16;
    float bq = bias[col];
    int which = col >> 10;          // 0=q 1=k 2=v
    int h = col & 1023;
    int head = h >> 6, d = h & 63;
    u16* dst = which == 0 ? Qo : (which == 1 ? Ko : Vo);
    float scale = which == 1 ? 0.125f : 1.0f;   // fold 1/sqrt(64) into K
#pragma unroll
    for (int m = 0; m < 4; ++m) {
#pragma unroll
      for (int r = 0; r < 4; ++r) {
        int row = m0 + wr * 64 + m * 16 + lg * 4 + r;
        int b = row >> 10, ii = row & 1023;
        float v = (acc[m][n][r] + bq) * scale;
        dst[(size_t)(((b * 16 + head) << 10) + ii) * 64 + d] = f2b(v);
      }
    }
  }
}

// ---------------- out = AO @ Wo^T + bo: same pipeline ----------------
__global__ __launch_bounds__(256) void gemm_out(const u16* __restrict__ A, const u16* __restrict__ Bw,
                                                const float* __restrict__ bias, float* __restrict__ Co) {
  __shared__ u16 As[3][4][128][8];
  __shared__ u16 Bs[3][4][128][8];
  const int orig = blockIdx.y * 8 + blockIdx.x;    // gridDim = (8, 32)
  const int xcd = orig & 7, q = orig >> 3;         // 32 blocks/XCD
  const int mt = (xcd << 2) + (q >> 3);            // 4 m-tiles
  const int nt = q & 7;                            // 8 n-tiles
  const int m0 = mt * 128, n0 = nt * 128;
  const int t = threadIdx.x, lane = t & 63, w = t >> 6;
  const int wr = w >> 1, wc = w & 1;
  const int l16 = lane & 15, lg = lane >> 4;
  f32x4 acc[4][4] = {};
  const int r0 = t & 127, g0 = t >> 7;
  const int g1 = g0 + 2;

#define STAGE(buf, k0) do { \
    GLDS(&A[(size_t)(m0 + r0) * 1024 + (k0) + g0 * 8], &As[buf][g0][r0][0]); \
    GLDS(&A[(size_t)(m0 + r0) * 1024 + (k0) + g1 * 8], &As[buf][g1][r0][0]); \
    GLDS(&Bw[(size_t)(n0 + r0) * 1024 + (k0) + g0 * 8], &Bs[buf][g0][r0][0]); \
    GLDS(&Bw[(size_t)(n0 + r0) * 1024 + (k0) + g1 * 8], &Bs[buf][g1][r0][0]); \
  } while (0)

  STAGE(0, 0);
  STAGE(1, 32);

  int buf = 0;
  for (int kt = 0; kt < 32; ++kt) {
    if (kt < 31) PIPE_WAIT(4); else PIPE_WAIT(0);
    if (kt < 30) {
      int nb = buf + 2; if (nb >= 3) nb -= 3;
      STAGE(nb, (kt + 2) * 32);
      __builtin_amdgcn_sched_barrier(0);
    }
    bf16x8 af[4], bfr[4];
#pragma unroll
    for (int m = 0; m < 4; ++m) af[m] = *(const bf16x8*)&As[buf][lg][wr * 64 + m * 16 + l16][0];
#pragma unroll
    for (int n = 0; n < 4; ++n) bfr[n] = *(const bf16x8*)&Bs[buf][lg][wc * 64 + n * 16 + l16][0];
#pragma unroll
    for (int m = 0; m < 4; ++m)
#pragma unroll
      for (int n = 0; n < 4; ++n) acc[m][n] = MFMA16(af[m], bfr[n], acc[m][n]);
    if (++buf == 3) buf = 0;
  }
#undef STAGE

#pragma unroll
  for (int n = 0; n < 4; ++n) {
    int col = n0 + wc * 64 + n * 16 + l16;
    float bq = bias[col];
#pragma unroll
    for (int m = 0; m < 4; ++m) {
#pragma unroll
      for (int r = 0; r < 4; ++r) {
        int row = m0 + wr * 64 + m * 16 + lg * 4 + r;
        Co[(size_t)row * 1024 + col] = acc[m][n][r] + bq;
      }
    }
  }
}

// ---------------- fused causal attention with relative bias ----------------
// grid (64 bn, 16 qtiles), 4 waves; wave w owns Q rows [16w,16w+16).
// F half-staged (parity ring, new 64 rows/iter). Bnd2 in gathered layout:
// writer scatters Band[il, il-jl+63] to [il][jl&15][jl>>4]; reader = 1 b64/r.
__global__ __launch_bounds__(256) void attn_kernel(const u16* __restrict__ Qg, const u16* __restrict__ Kg,
                                                   const u16* __restrict__ Vtg, const u16* __restrict__ Fg,
                                                   u16* __restrict__ AO) {
  __shared__ u16 Kl[4096];          // [j][d] swz
  __shared__ u16 Vl[4096];          // [d][j] swz
  __shared__ u16 Fl[8192];          // [t^par][d] swz, 128 rows, half-ring
  __shared__ u16 Bnd2[4][1024];     // per-wave gathered band [il][jl&15][jl>>4]
  __shared__ u16 Pl[4][1024];       // per-wave P [i_local][j] swz

  const int bn = blockIdx.x;
  const int b = bn >> 4, n = bn & 15;
  const int qt = 15 - (int)blockIdx.y;       // heavy tiles first
  const int i0 = qt * 64;
  const int t = threadIdx.x, lane = t & 63, w = t >> 6;
  const int l16 = lane & 15, lg = lane >> 4;

  const int rr0 = t >> 3, cc0 = t & 7;            // rows 0..31
  const int rr1 = (t + 256) >> 3, cc1 = t & 7;    // rows 32..63

  bf16x8 qf[2];
  {
    const u16* qp = &Qg[(size_t)((bn << 10) + i0 + (w << 4) + l16) * 64 + lg * 8];
    qf[0] = *(const bf16x8*)qp;
    qf[1] = *(const bf16x8*)(qp + 32);
  }

  // ---- prologue: stage F high half (rows 64..127 of window 0, par=0) ----
  {
    int mb0 = i0 - 63;
    int h0 = 64 + rr0, h1 = 64 + rr1;
    int gm0 = mb0 + h0; gm0 = gm0 < 0 ? 0 : (gm0 > 1023 ? 1023 : gm0);
    int gm1 = mb0 + h1; gm1 = gm1 < 0 ? 0 : (gm1 > 1023 ? 1023 : gm1);
    u16x8 a = *(const u16x8*)&Fg[(size_t)((n << 10) + gm0) * 64 + cc0 * 8];
    u16x8 c = *(const u16x8*)&Fg[(size_t)((n << 10) + gm1) * 64 + cc1 * 8];
    *(u16x8*)&Fl[h0 * 64 + (((cc0 ^ (h0 & 7)) & 7) << 3)] = a;
    *(u16x8*)&Fl[h1 * 64 + (((cc1 ^ (h1 & 7)) & 7) << 3)] = c;
  }

  float mrun[4], lsum[4];
  f32x4 ao[4] = {};
#pragma unroll
  for (int r = 0; r < 4; ++r) { mrun[r] = -3.0e38f; lsum[r] = 0.0f; }

  u16x8 rk0, rk1, rv0, rv1, rf0, rf1;

#define LOAD_STAGE(jt_) do { \
    int j0_ = (jt_) * 64, mb_ = i0 - j0_ - 63; \
    rk0 = *(const u16x8*)&Kg[(size_t)((bn << 10) + j0_ + rr0) * 64 + cc0 * 8]; \
    rk1 = *(const u16x8*)&Kg[(size_t)((bn << 10) + j0_ + rr1) * 64 + cc1 * 8]; \
    rv0 = *(const u16x8*)&Vtg[(size_t)((bn << 6) + rr0) * 1024 + j0_ + cc0 * 8]; \
    rv1 = *(const u16x8*)&Vtg[(size_t)((bn << 6) + rr1) * 1024 + j0_ + cc1 * 8]; \
    int m0_ = mb_ + rr0; m0_ = m0_ < 0 ? 0 : (m0_ > 1023 ? 1023 : m0_); \
    int m1_ = mb_ + rr1; m1_ = m1_ < 0 ? 0 : (m1_ > 1023 ? 1023 : m1_); \
    rf0 = *(const u16x8*)&Fg[(size_t)((n << 10) + m0_) * 64 + cc0 * 8]; \
    rf1 = *(const u16x8*)&Fg[(size_t)((n << 10) + m1_) * 64 + cc1 * 8]; \
  } while (0)

  LOAD_STAGE(0);

  for (int jt = 0; jt <= qt; ++jt) {
    const bool diag = (jt == qt);
    const int ph = (jt & 1) << 6;      // F half-ring parity

    // ---- write staged K/V + F-low(window jt) ----
    *(u16x8*)&Kl[rr0 * 64 + (((cc0 ^ (rr0 & 7)) & 7) << 3)] = rk0;
    *(u16x8*)&Kl[rr1 * 64 + (((cc1 ^ (rr1 & 7)) & 7) << 3)] = rk1;
    *(u16x8*)&Vl[rr0 * 64 + (((cc0 ^ (rr0 & 7)) & 7) << 3)] = rv0;
    *(u16x8*)&Vl[rr1 * 64 + (((cc1 ^ (rr1 & 7)) & 7) << 3)] = rv1;
    *(u16x8*)&Fl[(rr0 ^ ph) * 64 + (((cc0 ^ (rr0 & 7)) & 7) << 3)] = rf0;
    *(u16x8*)&Fl[(rr1 ^ ph) * 64 + (((cc1 ^ (rr1 & 7)) & 7) << 3)] = rf1;
    __syncthreads();

    if (jt < qt) LOAD_STAGE(jt + 1);   // T14: issue early, consumed next iter

    // ---- QK^T + band (MFMA cluster, setprio) ----
    __builtin_amdgcn_s_setprio(1);
    f32x4 sc[4] = {};
#pragma unroll
    for (int kk = 0; kk < 2; ++kk)
#pragma unroll
      for (int nn = 0; nn < 4; ++nn) {
        int jr = nn * 16 + l16;
        bf16x8 kb = *(const bf16x8*)&Kl[jr * 64 + ((((lg + 4 * kk) ^ (jr & 7)) & 7) << 3)];
        sc[nn] = MFMA16(qf[kk], kb, sc[nn]);
      }
    f32x4 bb[5] = {};
#pragma unroll
    for (int kk = 0; kk < 2; ++kk)
#pragma unroll
      for (int ct = 0; ct < 5; ++ct) {
        int trow = (w << 4) + ct * 16 + l16;
        bf16x8 fb = *(const bf16x8*)&Fl[(trow ^ ph) * 64 + ((((lg + 4 * kk) ^ (trow & 7)) & 7) << 3)];
        bb[ct] = MFMA16(qf[kk], fb, bb[ct]);
      }
    __builtin_amdgcn_s_setprio(0);

    // ---- scatter band to gathered layout ----
#pragma unroll
    for (int ct = 0; ct < 5; ++ct)
#pragma unroll
      for (int r = 0; r < 4; ++r) {
        int il = lg * 4 + r;
        int jl = il + 63 - (ct * 16 + l16);
        if ((unsigned)jl < 64u)
          Bnd2[w][il * 64 + ((jl & 15) << 2) + (jl >> 4)] = f2b(bb[ct][r]);
      }
    WAVE_LDS_FENCE();   // Bnd2 wave-private

    // ---- softmax: band read = 1 b64 per r ----
    float pv[4][4];
#pragma unroll
    for (int r = 0; r < 4; ++r) {
      int il = lg * 4 + r;
      u16x4 gv = *(const u16x4*)&Bnd2[w][il * 64 + (l16 << 2)];
      float stmp[4];
      float mx = -3.0e38f;
#pragma unroll
      for (int nn = 0; nn < 4; ++nn) {
        int jl = nn * 16 + l16;
        float s = sc[nn][r] + b2f(gv[nn]);
        if (diag && jl > (w << 4) + il) s = -1.0e30f;   // j > i
        stmp[nn] = s;
        mx = fmaxf(mx, s);
      }
#pragma unroll
      for (int off = 1; off < 16; off <<= 1) mx = fmaxf(mx, __shfl_xor(mx, off));
      float mnew = fmaxf(mrun[r], mx);
      float scl = __expf(mrun[r] - mnew);
      float rs = 0.0f;
#pragma unroll
      for (int nn = 0; nn < 4; ++nn) {
        pv[nn][r] = __expf(stmp[nn] - mnew);
        rs += pv[nn][r];
      }
      lsum[r] = lsum[r] * scl + rs;    // per-lane partial; butterfly at end
      mrun[r] = mnew;
#pragma unroll
      for (int nd = 0; nd < 4; ++nd) ao[nd][r] *= scl;
    }

    // ---- P -> LDS (swizzled row-major), PV ----
#pragma unroll
    for (int nn = 0; nn < 4; ++nn)
#pragma unroll
      for (int r = 0; r < 4; ++r) {
        int i = lg * 4 + r, j = nn * 16 + l16;
        Pl[w][i * 64 + ((((j >> 3) ^ (i & 7)) & 7) << 3) + (j & 7)] = f2b(pv[nn][r]);
      }
    WAVE_LDS_FENCE();   // Pl wave-private
    __builtin_amdgcn_s_setprio(1);
#pragma unroll
    for (int kk = 0; kk < 2; ++kk) {
      bf16x8 pa = *(const bf16x8*)&Pl[w][l16 * 64 + ((((lg + 4 * kk) ^ (l16 & 7)) & 7) << 3)];
#pragma unroll
      for (int nd = 0; nd < 4; ++nd) {
        int dr = nd * 16 + l16;
        bf16x8 vb = *(const bf16x8*)&Vl[dr * 64 + ((((lg + 4 * kk) ^ (dr & 7)) & 7) << 3)];
        ao[nd] = MFMA16(pa, vb, ao[nd]);
      }
    }
    __builtin_amdgcn_s_setprio(0);
    __syncthreads();   // protect Kl/Vl/Fl for next iteration
  }

  // ---- finalize row sums, normalize + write ----
#pragma unroll
  for (int r = 0; r < 4; ++r)
#pragma unroll
    for (int off = 1; off < 16; off <<= 1) lsum[r] += __shfl_xor(lsum[r], off);

#pragma unroll
  for (int nd = 0; nd < 4; ++nd)
#pragma unroll
    for (int r = 0; r < 4; ++r) {
      int i = i0 + (w << 4) + lg * 4 + r;
      int d = nd * 16 + l16;
      float v = ao[nd][r] / lsum[r];
      AO[(size_t)((b << 10) + i) * 1024 + n * 64 + d] = f2b(v);
    }
#undef LOAD_STAGE
}

// ---------------- launch ----------------
extern "C" void kernel_launch(void* const* d_in, const int* in_sizes, int n_in,
                              void* d_out, int out_size, void* d_ws, size_t ws_size,
                              hipStream_t stream) {
  (void)in_sizes; (void)n_in; (void)out_size; (void)ws_size;
  const float* x    = (const float*)d_in[0];
  // d_in[1] = mask: always causal triu(k=1) -> analytic
  const float* Wqkv = (const float*)d_in[2];
  const float* bqkv = (const float*)d_in[3];
  const float* Wo   = (const float*)d_in[4];
  const float* bo   = (const float*)d_in[5];
  const float* Er   = (const float*)d_in[6];
  float* out = (float*)d_out;

  char* p = (char*)d_ws;
  u16* xb    = (u16*)p; p += (size_t)4096 * 1024 * 2;
  u16* wqkvb = (u16*)p; p += (size_t)3072 * 1024 * 2;
  u16* wob   = (u16*)p; p += (size_t)1024 * 1024 * 2;
  u16* Fb    = (u16*)p; p += (size_t)16 * 1024 * 64 * 2;
  u16* Qb    = (u16*)p; p += (size_t)64 * 1024 * 64 * 2;
  u16* Kb    = (u16*)p; p += (size_t)64 * 1024 * 64 * 2;
  u16* Vb    = (u16*)p; p += (size_t)64 * 1024 * 64 * 2;
  u16* Vtb   = (u16*)p; p += (size_t)64 * 1024 * 64 * 2;   // V^T (bn, d, i)
  u16* AO    = (u16*)p; p += (size_t)4096 * 1024 * 2;

  cvt_all<<<8192, 256, 0, stream>>>(x, xb, Wqkv, wqkvb, Wo, wob);
  build_F<<<1024, 256, 0, stream>>>(Er, Fb);
  gemm_qkv<<<dim3(24, 32), 256, 0, stream>>>(xb, wqkvb, bqkv, Qb, Kb, Vb);
  transpose_v<<<dim3(64, 16), 256, 0, stream>>>(Vb, Vtb);
  attn_kernel<<<dim3(64, 16), 256, 0, stream>>>(Qb, Kb, Vtb, Fb, AO);
  gemm_out<<<dim3(8, 32), 256, 0, stream>>>(AO, wob, bo, out);
}